// Round 13
// baseline (355.791 us; speedup 1.0000x reference)
//
#include <hip/hip_runtime.h>
#include <stdint.h>

#define S_LEN 4096
#define D_DIM 2048
#define NHEAD 16
#define HDIM  128

typedef short bf16x8 __attribute__((ext_vector_type(8)));
typedef float f32x4  __attribute__((ext_vector_type(4)));
typedef float f32x16 __attribute__((ext_vector_type(16)));

__device__ __forceinline__ unsigned short f2bf(float x) {
  union { float f; unsigned u; } v; v.f = x;
  unsigned r = v.u + 0x7FFFu + ((v.u >> 16) & 1u);  // RNE
  return (unsigned short)(r >> 16);
}

__device__ __forceinline__ float bf2f(unsigned short s) {
  union { unsigned u; float f; } v; v.u = ((unsigned)s) << 16;
  return v.f;
}

__device__ __forceinline__ unsigned cvtpk_bf16(float lo, float hi_) {
  unsigned r;
  asm("v_cvt_pk_bf16_f32 %0, %1, %2" : "=v"(r) : "v"(lo), "v"(hi_));
  return r;
}

__device__ __forceinline__ void gload_lds16(const void* g, void* l) {
  __builtin_amdgcn_global_load_lds(
      (const __attribute__((address_space(1))) unsigned int*)g,
      (__attribute__((address_space(3))) unsigned int*)l, 16, 0, 0);
}

// ---------------- fused fp32 -> bf16 convert (X + 4 weights, one launch) ---
__global__ __launch_bounds__(256) void cvt_all(
    const float* __restrict__ X, const float* __restrict__ Wq,
    const float* __restrict__ Wk, const float* __restrict__ Wv,
    const float* __restrict__ Wo, unsigned short* __restrict__ out) {
  const size_t DD = (size_t)D_DIM * D_DIM;
  size_t i = ((size_t)blockIdx.x * 256 + threadIdx.x) * 8;
  const float* src; size_t off;
  if (i < 2 * DD)      { src = X;  off = i; }
  else if (i < 3 * DD) { src = Wq; off = i - 2 * DD; }
  else if (i < 4 * DD) { src = Wk; off = i - 3 * DD; }
  else if (i < 5 * DD) { src = Wv; off = i - 4 * DD; }
  else                 { src = Wo; off = i - 5 * DD; }
  float4 a = *(const float4*)(src + off);
  float4 b = *(const float4*)(src + off + 4);
  union { unsigned short s[8]; bf16x8 v; } o;
  o.s[0] = f2bf(a.x); o.s[1] = f2bf(a.y); o.s[2] = f2bf(a.z); o.s[3] = f2bf(a.w);
  o.s[4] = f2bf(b.x); o.s[5] = f2bf(b.y); o.s[6] = f2bf(b.z); o.s[7] = f2bf(b.w);
  *(bf16x8*)(out + i) = o.v;
}

// ============ 8-phase 256x256 QKV GEMM =====================================
// BM=BN=256, BK=64, 8 waves. Wave output: rows {wm*64+[0,64)} from EACH
// A-half, cols {wn*32+[0,32)} from EACH B-half => phase (pa,pb) has ALL
// waves reading one (A-half,B-half) pair. Deadness: Ah0 dies after P2,
// Bh0 after P3, Ah1/Bh1 after P4 (buf1: P5-P8). Stage schedule
// P1..P8 = Ah1(t1),Bh1(t1),Ah0(t2),Bh0(t2),Ah1(t2),Bh1(t2),Ah0(t3),Bh0(t3):
// each stage targets a dead region (proof: every wave passed lgkmcnt(0)
// before prior B2). vmcnt(4) at P4/P8 only: 12 outstanding -> 8 oldest
// done = the 4 halves the next 4 phases read. Full-XOR swizzle (r10: 0
// conflicts). launch_bounds(512,1): VGPR cap 256 (arg2=2 would spill).
__device__ __forceinline__ void stage_half(
    const unsigned short* __restrict__ src, unsigned short* lds,
    int rc0, int t, int h, int wv, int lane) {
#pragma unroll
  for (int p = 0; p < 2; ++p) {
    const int off = wv * 2048 + p * 1024;      // wave-uniform byte base in half
    const int o = off + lane * 16;             // linear dest byte offset
    const int row = o >> 7, ch = (o >> 4) & 7;
    gload_lds16(src + (size_t)(rc0 + h * 128 + row) * 2048 + t * 64 + ((ch ^ (row & 7)) << 3),
                lds + h * 8192 + (off >> 1));
  }
}

template<int PA, int PB>
__device__ __forceinline__ void phase(
    f32x4 (&acc)[8][4], const unsigned short* Abuf, const unsigned short* Bbuf,
    const unsigned short* __restrict__ A, const unsigned short* __restrict__ W,
    unsigned short* stLA, unsigned short* stLB,
    int m0, int n0, int sm, int sh, int stT, int vm,
    int wm, int wn, int rA, int g4, int wv, int lane) {
  const unsigned short* Ab = Abuf + PA * 8192;
  const unsigned short* Bb = Bbuf + PB * 8192;
  bf16x8 af0[4], af1[4], bf0[2], bf1[2];
  const int s0 = (g4 ^ (rA & 7)) << 3, s1 = ((4 + g4) ^ (rA & 7)) << 3;
#pragma unroll
  for (int i = 0; i < 4; ++i) {
    const int rr = (wm * 64 + i * 16 + rA) * 64;
    af0[i] = *(const bf16x8*)(Ab + rr + s0);
    af1[i] = *(const bf16x8*)(Ab + rr + s1);
  }
#pragma unroll
  for (int j = 0; j < 2; ++j) {
    const int rr = (wn * 32 + j * 16 + rA) * 64;
    bf0[j] = *(const bf16x8*)(Bb + rr + s0);
    bf1[j] = *(const bf16x8*)(Bb + rr + s1);
  }
  if (stT < 32) {
    if (sm == 0) stage_half(A, stLA, m0, stT, sh, wv, lane);
    else         stage_half(W, stLB, n0, stT, sh, wv, lane);
  }
  __builtin_amdgcn_s_barrier();
  asm volatile("s_waitcnt lgkmcnt(0)" ::: "memory");
  __builtin_amdgcn_sched_barrier(0);
  __builtin_amdgcn_s_setprio(1);
#pragma unroll
  for (int i = 0; i < 4; ++i)
#pragma unroll
    for (int j = 0; j < 2; ++j)
      acc[PA * 4 + i][PB * 2 + j] =
          __builtin_amdgcn_mfma_f32_16x16x32_bf16(af0[i], bf0[j], acc[PA * 4 + i][PB * 2 + j], 0, 0, 0);
#pragma unroll
  for (int i = 0; i < 4; ++i)
#pragma unroll
    for (int j = 0; j < 2; ++j)
      acc[PA * 4 + i][PB * 2 + j] =
          __builtin_amdgcn_mfma_f32_16x16x32_bf16(af1[i], bf1[j], acc[PA * 4 + i][PB * 2 + j], 0, 0, 0);
  __builtin_amdgcn_s_setprio(0);
  if (vm == 1) asm volatile("s_waitcnt vmcnt(4)" ::: "memory");
  if (vm == 2) asm volatile("s_waitcnt vmcnt(0)" ::: "memory");
  __builtin_amdgcn_s_barrier();
  __builtin_amdgcn_sched_barrier(0);
  asm volatile("" ::: "memory");
}

__global__ __launch_bounds__(512, 1) void gemm_qkv8(
    const unsigned short* __restrict__ A, const unsigned short* __restrict__ W,
    const float* __restrict__ bq, const float* __restrict__ bk,
    const float* __restrict__ bv, unsigned short* __restrict__ Q,
    unsigned short* __restrict__ Ko, unsigned short* __restrict__ V,
    float qsc) {
  __shared__ __attribute__((aligned(16))) unsigned short LA[2][16384];  // 2 halves x 128x64
  __shared__ __attribute__((aligned(16))) unsigned short LB[2][16384];
  const int bid = blockIdx.x;
  const int swz = (bid & 7) * 48 + (bid >> 3);   // 384 % 8 == 0: bijective
  const int m0 = (swz / 24) * 256, n0 = (swz % 24) * 256;
  const int tid = threadIdx.x, lane = tid & 63, wv = tid >> 6;
  const int wm = wv >> 2, wn = wv & 3;
  const int rA = lane & 15, g4 = lane >> 4;

  f32x4 acc[8][4];
#pragma unroll
  for (int i = 0; i < 8; ++i)
#pragma unroll
    for (int j = 0; j < 4; ++j)
#pragma unroll
      for (int r = 0; r < 4; ++r) acc[i][j][r] = 0.f;

  // ---- prologue: t0 all 4 halves + t1 Ah0,Bh0 (12 loads); wait t0 ----
  stage_half(A, &LA[0][0], m0, 0, 0, wv, lane);
  stage_half(W, &LB[0][0], n0, 0, 0, wv, lane);
  stage_half(A, &LA[0][0], m0, 0, 1, wv, lane);
  stage_half(W, &LB[0][0], n0, 0, 1, wv, lane);
  stage_half(A, &LA[1][0], m0, 1, 0, wv, lane);
  stage_half(W, &LB[1][0], n0, 1, 0, wv, lane);
  asm volatile("s_waitcnt vmcnt(4)" ::: "memory");
  __builtin_amdgcn_s_barrier();
  __builtin_amdgcn_sched_barrier(0);

  for (int i = 0; i < 16; ++i) {
    const int t1 = 2 * i + 1, t2 = 2 * i + 2, t3 = 2 * i + 3;
    const int vm4 = (i == 15) ? 2 : 1;   // last iter: drain (t2 skipped)
    const int vm8 = (i == 15) ? 0 : 1;   // last iter: nothing left to read
    // phases computing buf0 (tile 2i):
    phase<0, 0>(acc, &LA[0][0], &LB[0][0], A, W, &LA[1][0], &LB[1][0], m0, n0, 0, 1, t1, 0, wm, wn, rA, g4, wv, lane);
    phase<0, 1>(acc, &LA[0][0], &LB[0][0], A, W, &LA[1][0], &LB[1][0], m0, n0, 1, 1, t1, 0, wm, wn, rA, g4, wv, lane);
    phase<1, 0>(acc, &LA[0][0], &LB[0][0], A, W, &LA[0][0], &LB[0][0], m0, n0, 0, 0, t2, 0, wm, wn, rA, g4, wv, lane);
    phase<1, 1>(acc, &LA[0][0], &LB[0][0], A, W, &LA[0][0], &LB[0][0], m0, n0, 1, 0, t2, vm4, wm, wn, rA, g4, wv, lane);
    // phases computing buf1 (tile 2i+1):
    phase<0, 0>(acc, &LA[1][0], &LB[1][0], A, W, &LA[0][0], &LB[0][0], m0, n0, 0, 1, t2, 0, wm, wn, rA, g4, wv, lane);
    phase<0, 1>(acc, &LA[1][0], &LB[1][0], A, W, &LA[0][0], &LB[0][0], m0, n0, 1, 1, t2, 0, wm, wn, rA, g4, wv, lane);
    phase<1, 0>(acc, &LA[1][0], &LB[1][0], A, W, &LA[1][0], &LB[1][0], m0, n0, 0, 0, t3, 0, wm, wn, rA, g4, wv, lane);
    phase<1, 1>(acc, &LA[1][0], &LB[1][0], A, W, &LA[1][0], &LB[1][0], m0, n0, 1, 0, t3, vm8, wm, wn, rA, g4, wv, lane);
  }

  // ---- epilogue: bias + seg routing (256-tile never straddles 2048) ----
  const int seg = n0 >> 11;
  const float* bp = (seg == 0) ? bq : (seg == 1) ? bk : bv;
  unsigned short* op = (seg == 0) ? Q : (seg == 1) ? Ko : V;
  const float es = (seg == 0) ? qsc : 1.0f;
  const int cR = g4 * 4, cC = rA;
#pragma unroll
  for (int J = 0; J < 4; ++J) {
    const int cl = (n0 & 2047) + (J >> 1) * 128 + wn * 32 + (J & 1) * 16 + cC;
    const float bvv = bp[cl];
#pragma unroll
    for (int I = 0; I < 8; ++I) {
      const int row0 = m0 + (I >> 2) * 128 + wm * 64 + (I & 3) * 16 + cR;
#pragma unroll
      for (int r = 0; r < 4; ++r)
        op[(size_t)(row0 + r) * D_DIM + cl] = f2bf((acc[I][J][r] + bvv) * es);
    }
  }
}

// ---------------- O-projection GEMM (fp32 out + bias, m97 128^2) -----------
__global__ __launch_bounds__(256, 2) void gemm_bt_f32(
    const unsigned short* __restrict__ A, const unsigned short* __restrict__ B,
    const float* __restrict__ bias, float* __restrict__ Cout,
    int M, int N, int K) {
  __shared__ __attribute__((aligned(16))) unsigned short As[128 * 32];
  __shared__ __attribute__((aligned(16))) unsigned short Bs[128 * 32];
  const int m0 = blockIdx.y * 128, n0 = blockIdx.x * 128;
  const int tid = threadIdx.x, lane = tid & 63, wv = tid >> 6;
  const int wm = wv >> 1, wn = wv & 1;
  const int rA = lane & 15, kb = (lane >> 4) * 8;

  f32x4 acc[4][4];
#pragma unroll
  for (int i = 0; i < 4; ++i)
#pragma unroll
    for (int j = 0; j < 4; ++j)
#pragma unroll
      for (int r = 0; r < 4; ++r) acc[i][j][r] = 0.f;

  for (int k0 = 0; k0 < K; k0 += 32) {
    __syncthreads();
#pragma unroll
    for (int p = 0; p < 2; ++p) {
      const int rr = (wv * 2 + p) * 16 + (lane >> 2);
      const int cc = lane & 3;
      gload_lds16(A + (size_t)(m0 + rr) * K + k0 + cc * 8, As + (wv * 2 + p) * 512);
      gload_lds16(B + (size_t)(n0 + rr) * K + k0 + cc * 8, Bs + (wv * 2 + p) * 512);
    }
    __syncthreads();
    bf16x8 af[4], bfr[4];
#pragma unroll
    for (int i = 0; i < 4; ++i)
      af[i] = *(const bf16x8*)(As + (wm * 64 + i * 16 + rA) * 32 + kb);
#pragma unroll
    for (int j = 0; j < 4; ++j)
      bfr[j] = *(const bf16x8*)(Bs + (wn * 64 + j * 16 + rA) * 32 + kb);
#pragma unroll
    for (int i = 0; i < 4; ++i)
#pragma unroll
      for (int j = 0; j < 4; ++j)
        acc[i][j] = __builtin_amdgcn_mfma_f32_16x16x32_bf16(af[i], bfr[j], acc[i][j], 0, 0, 0);
  }

  const int cR = (lane >> 4) * 4, cC = lane & 15;
#pragma unroll
  for (int j = 0; j < 4; ++j) {
    const int col = n0 + wn * 64 + j * 16 + cC;
    const float bvv = bias[col];
#pragma unroll
    for (int i = 0; i < 4; ++i) {
      const int row0 = m0 + wm * 64 + i * 16 + cR;
#pragma unroll
      for (int r = 0; r < 4; ++r)
        Cout[(size_t)(row0 + r) * N + col] = acc[i][j][r] + bvv;
    }
  }
}

// ---------------- split-k causal flash attention (r9 measured-best form) ---
__global__ __launch_bounds__(256, 2) void attn_part(
    const unsigned short* __restrict__ Qb, const unsigned short* __restrict__ Kb,
    const unsigned short* __restrict__ Vb, unsigned short* __restrict__ Opart,
    float* __restrict__ ML) {
  __shared__ __attribute__((aligned(16))) unsigned short Ks[64 * 128];
  __shared__ __attribute__((aligned(16))) unsigned short Vt[128 * 64];
  const int bid = blockIdx.x;
  const int h  = ((bid & 7) << 1) | ((bid >> 3) & 1);  // XCD-grouped heads
  const int hf = (bid >> 4) & 1;
  const int qi = 31 - (bid >> 5);                      // heavy first
  const int q0 = qi * 128;
  const int u2 = (h * 32 + qi) * 2 + hf;
  const int tid = threadIdx.x, lane = tid & 63, wv = tid >> 6;
  const int qc = lane & 31, hi = lane >> 5;
  const int q0w = q0 + wv * 32;
  const int myq = q0w + qc;
  const int kp = tid & 31, hb = (tid >> 5) * 16;

  bf16x8 qf[8];
#pragma unroll
  for (int sl = 0; sl < 8; ++sl)
    qf[sl] = *(const bf16x8*)(Qb + (size_t)myq * D_DIM + h * HDIM + sl * 16 + hi * 8);

  f32x16 oacc[4];
#pragma unroll
  for (int nf = 0; nf < 4; ++nf)
#pragma unroll
    for (int r = 0; r < 16; ++r) oacc[nf][r] = 0.f;
  float mh = -3.0e38f, l = 0.f;

  const int klo = hf * (qi + 1), khi = klo + qi + 1;
  const int wqmax = q0w + 31;

  for (int kt = klo; kt < khi; ++kt) {
    const int k0 = kt * 64;
    __syncthreads();
#pragma unroll
    for (int p = 0; p < 4; ++p) {
      const int ob = wv * 4096 + p * 1024;
      const int o = ob + lane * 16;
      const int r = o >> 8, c = (o >> 4) & 15;
      gload_lds16(Kb + (size_t)(k0 + r) * D_DIM + h * HDIM + (c ^ (r & 7)) * 8,
                  Ks + ob / 2);
    }
    {
      const unsigned short* s0 = Vb + (size_t)(k0 + 2 * kp) * D_DIM + h * HDIM + hb;
      union { uint4 u[4]; unsigned short s[32]; } t;
      t.u[0] = *(const uint4*)s0;           t.u[1] = *(const uint4*)(s0 + 8);
      t.u[2] = *(const uint4*)(s0 + D_DIM); t.u[3] = *(const uint4*)(s0 + D_DIM + 8);
#pragma unroll
      for (int w = 0; w < 16; ++w) {
        const int hd = hb + w;
        const unsigned val = (unsigned)t.s[w] | ((unsigned)t.s[16 + w] << 16);
        *(unsigned*)((char*)Vt + hd * 128 + (((kp >> 2) ^ (hd & 7)) << 4) + ((kp & 3) << 2)) = val;
      }
    }
    __syncthreads();
    if (k0 > wqmax) continue;

    f32x16 sacc[2];
#pragma unroll
    for (int kb = 0; kb < 2; ++kb)
#pragma unroll
      for (int r = 0; r < 16; ++r) sacc[kb][r] = 0.f;
    __builtin_amdgcn_s_setprio(1);
#pragma unroll
    for (int sl = 0; sl < 8; ++sl) {
#pragma unroll
      for (int kb = 0; kb < 2; ++kb) {
        const int row = kb * 32 + qc;
        bf16x8 kfr = *(const bf16x8*)((const char*)Ks + row * 256 +
                                      (((2 * sl + hi) ^ (qc & 7)) << 4));
        sacc[kb] = __builtin_amdgcn_mfma_f32_32x32x16_bf16(kfr, qf[sl], sacc[kb], 0, 0, 0);
      }
    }
    __builtin_amdgcn_s_setprio(0);

    const bool needmask = (k0 + 63 > q0w);
    if (needmask) {
      const int dq = myq - k0;
#pragma unroll
      for (int kb = 0; kb < 2; ++kb)
#pragma unroll
        for (int r = 0; r < 16; ++r) {
          const int kk = kb * 32 + (r & 3) + 8 * (r >> 2) + 4 * hi;
          if (kk > dq) sacc[kb][r] = -3.0e38f;
        }
    }
    float mx0[8];
#pragma unroll
    for (int t = 0; t < 8; ++t)
      mx0[t] = fmaxf(fmaxf(sacc[0][t], sacc[0][t + 8]),
                     fmaxf(sacc[1][t], sacc[1][t + 8]));
    float mx = fmaxf(fmaxf(fmaxf(mx0[0], mx0[1]), fmaxf(mx0[2], mx0[3])),
                     fmaxf(fmaxf(mx0[4], mx0[5]), fmaxf(mx0[6], mx0[7])));
    mx = fmaxf(mx, __shfl_xor(mx, 32));
    if (!__all(mx <= mh + 11.5f)) {
      const float mnew = fmaxf(mh, mx);
      const float corr = exp2f(mh - mnew);
      mh = mnew;
      l *= corr;
#pragma unroll
      for (int r = 0; r < 16; ++r) {
        const float cr = __shfl(corr, (r & 3) + 8 * (r >> 2) + 4 * hi);
#pragma unroll
        for (int nf = 0; nf < 4; ++nf) oacc[nf][r] *= cr;
      }
    }
    float rs = 0.f;
#pragma unroll
    for (int kb = 0; kb < 2; ++kb)
#pragma unroll
      for (int r = 0; r < 16; ++r) {
        const float p = exp2f(sacc[kb][r] - mh);
        sacc[kb][r] = p;
        rs += p;
      }
    rs += __shfl_xor(rs, 32);
    l += rs;

    bf16x8 pa[4];
#pragma unroll
    for (int kb = 0; kb < 2; ++kb)
#pragma unroll
      for (int s = 0; s < 2; ++s) {
        const int b = s * 8;
        unsigned pk0 = cvtpk_bf16(sacc[kb][b + 0], sacc[kb][b + 1]);
        unsigned pk1 = cvtpk_bf16(sacc[kb][b + 2], sacc[kb][b + 3]);
        unsigned pk2 = cvtpk_bf16(sacc[kb][b + 4], sacc[kb][b + 5]);
        unsigned pk3 = cvtpk_bf16(sacc[kb][b + 6], sacc[kb][b + 7]);
        const unsigned sw0 = (unsigned)__shfl_xor((int)pk0, 32);
        const unsigned sw1 = (unsigned)__shfl_xor((int)pk1, 32);
        const unsigned sw2 = (unsigned)__shfl_xor((int)pk2, 32);
        const unsigned sw3 = (unsigned)__shfl_xor((int)pk3, 32);
        union { unsigned u[4]; bf16x8 v; } f;
        if (hi) { f.u[0] = sw2; f.u[1] = sw3; f.u[2] = pk2; f.u[3] = pk3; }
        else    { f.u[0] = pk0; f.u[1] = pk1; f.u[2] = sw0; f.u[3] = sw1; }
        pa[kb * 2 + s] = f.v;
      }

    __builtin_amdgcn_s_setprio(1);
#pragma unroll
    for (int nf = 0; nf < 4; ++nf) {
      const int hd = 32 * nf + qc;
#pragma unroll
      for (int ks = 0; ks < 4; ++ks) {
        bf16x8 vf = *(const bf16x8*)((const char*)Vt + hd * 128 +
                                     (((2 * ks + hi) ^ (qc & 7)) << 4));
        oacc[nf] = __builtin_amdgcn_mfma_f32_32x32x16_bf16(pa[ks], vf, oacc[nf], 0, 0, 0);
      }
    }
    __builtin_amdgcn_s_setprio(0);
  }

  unsigned short* ob = Opart + (size_t)u2 * 16384;
#pragma unroll
  for (int r = 0; r < 16; ++r) {
    const int rl = wv * 32 + (r & 3) + 8 * (r >> 2) + 4 * hi;
#pragma unroll
    for (int nf = 0; nf < 4; ++nf)
      ob[rl * 128 + 32 * nf + qc] = f2bf(oacc[nf][r]);
  }
  if (hi == 0) {
    ML[(size_t)u2 * 256 + wv * 32 + qc] = mh;
    ML[(size_t)u2 * 256 + 128 + wv * 32 + qc] = l;
  }
}

// ---------------- combine the two k-halves -------------------------------
__global__ __launch_bounds__(256) void attn_combine(
    const unsigned short* __restrict__ Opart, const float* __restrict__ ML,
    unsigned short* __restrict__ Ob) {
  const int u = blockIdx.x;            // h*32 + qi
  const int h = u >> 5, qi = u & 31;
  const int tid = threadIdx.x;
  const int row = tid >> 1, c0 = (tid & 1) * 64;
  const float m1 = ML[(size_t)(u * 2 + 0) * 256 + row];
  const float l1 = ML[(size_t)(u * 2 + 0) * 256 + 128 + row];
  const float m2 = ML[(size_t)(u * 2 + 1) * 256 + row];
  const float l2 = ML[(size_t)(u * 2 + 1) * 256 + 128 + row];
  const float M  = fmaxf(m1, m2);
  const float a1 = exp2f(m1 - M), a2 = exp2f(m2 - M);
  const float inv = 1.f / (a1 * l1 + a2 * l2);
  const unsigned short* p1 = Opart + (size_t)(u * 2 + 0) * 16384 + row * 128 + c0;
  const unsigned short* p2 = Opart + (size_t)(u * 2 + 1) * 16384 + row * 128 + c0;
  unsigned short* o = Ob + (size_t)(qi * 128 + row) * D_DIM + h * HDIM + c0;
#pragma unroll
  for (int c = 0; c < 64; c += 8) {
    bf16x8 v1 = *(const bf16x8*)(p1 + c);
    bf16x8 v2 = *(const bf16x8*)(p2 + c);
    union { unsigned short s[8]; bf16x8 v; } out;
#pragma unroll
    for (int e = 0; e < 8; ++e)
      out.s[e] = f2bf((bf2f((unsigned short)v1[e]) * a1 +
                       bf2f((unsigned short)v2[e]) * a2) * inv);
    *(bf16x8*)(o + c) = out.v;
  }
}

extern "C" void kernel_launch(void* const* d_in, const int* in_sizes, int n_in,
                              void* d_out, int out_size, void* d_ws, size_t ws_size,
                              hipStream_t stream) {
  const float* X  = (const float*)d_in[0];
  const float* Wq = (const float*)d_in[1];
  const float* bq = (const float*)d_in[2];
  const float* Wk = (const float*)d_in[3];
  const float* bk = (const float*)d_in[4];
  const float* Wv = (const float*)d_in[5];
  const float* bv = (const float*)d_in[6];
  const float* Wo = (const float*)d_in[7];
  const float* bo = (const float*)d_in[8];
  float* out = (float*)d_out;

  unsigned short* ws = (unsigned short*)d_ws;
  const size_t SD = (size_t)S_LEN * D_DIM;
  const size_t DD = (size_t)D_DIM * D_DIM;
  unsigned short* Xb  = ws;
  unsigned short* Wqb = Xb + SD;        // Wq,Wk,Wv contiguous = fused [6144][2048]
  unsigned short* Wob = Wqb + 3 * DD;
  unsigned short* Qb  = Wob + DD;
  unsigned short* Kb  = Qb + SD;
  unsigned short* Vb  = Kb + SD;
  unsigned short* AOb = Vb + SD;
  unsigned short* Opart = ws;                 // 1024 units * 16384 = SD+2DD elems
  float* ML = (float*)(ws + SD + 2 * DD);     // 1024*256 f32 (tail of fused W)

  cvt_all<<<(int)(6 * DD / 8 / 256), 256, 0, stream>>>(X, Wq, Wk, Wv, Wo, Xb);

  const float qsc = 0.08838834764831845f * 1.4426950408889634f;  // scale*log2(e)
  gemm_qkv8<<<dim3(384), 512, 0, stream>>>(Xb, Wqb, bq, bk, bv, Qb, Kb, Vb, qsc);

  attn_part<<<dim3(1024), 256, 0, stream>>>(Qb, Kb, Vb, Opart, ML);
  attn_combine<<<dim3(512), 256, 0, stream>>>(Opart, ML, AOb);

  gemm_bt_f32<<<dim3(16, 32), 256, 0, stream>>>(AOb, Wob, bo, out, S_LEN, D_DIM, D_DIM);
}

// Round 14
// 316.516 us; speedup vs baseline: 1.1241x; 1.1241x over previous
//
#include <hip/hip_runtime.h>
#include <stdint.h>

#define S_LEN 4096
#define D_DIM 2048
#define NHEAD 16
#define HDIM  128

typedef short bf16x8 __attribute__((ext_vector_type(8)));
typedef float f32x4  __attribute__((ext_vector_type(4)));
typedef float f32x16 __attribute__((ext_vector_type(16)));

__device__ __forceinline__ unsigned short f2bf(float x) {
  union { float f; unsigned u; } v; v.f = x;
  unsigned r = v.u + 0x7FFFu + ((v.u >> 16) & 1u);  // RNE
  return (unsigned short)(r >> 16);
}

__device__ __forceinline__ float bf2f(unsigned short s) {
  union { unsigned u; float f; } v; v.u = ((unsigned)s) << 16;
  return v.f;
}

__device__ __forceinline__ unsigned cvtpk_bf16(float lo, float hi_) {
  unsigned r;
  asm("v_cvt_pk_bf16_f32 %0, %1, %2" : "=v"(r) : "v"(lo), "v"(hi_));
  return r;
}

__device__ __forceinline__ void gload_lds16(const void* g, void* l) {
  __builtin_amdgcn_global_load_lds(
      (const __attribute__((address_space(1))) unsigned int*)g,
      (__attribute__((address_space(3))) unsigned int*)l, 16, 0, 0);
}

// ---------------- fused fp32 -> bf16 convert (X + 4 weights, one launch) ---
__global__ __launch_bounds__(256) void cvt_all(
    const float* __restrict__ X, const float* __restrict__ Wq,
    const float* __restrict__ Wk, const float* __restrict__ Wv,
    const float* __restrict__ Wo, unsigned short* __restrict__ out) {
  const size_t DD = (size_t)D_DIM * D_DIM;
  size_t i = ((size_t)blockIdx.x * 256 + threadIdx.x) * 8;
  const float* src; size_t off;
  if (i < 2 * DD)      { src = X;  off = i; }
  else if (i < 3 * DD) { src = Wq; off = i - 2 * DD; }
  else if (i < 4 * DD) { src = Wk; off = i - 3 * DD; }
  else if (i < 5 * DD) { src = Wv; off = i - 4 * DD; }
  else                 { src = Wo; off = i - 5 * DD; }
  float4 a = *(const float4*)(src + off);
  float4 b = *(const float4*)(src + off + 4);
  union { unsigned short s[8]; bf16x8 v; } o;
  o.s[0] = f2bf(a.x); o.s[1] = f2bf(a.y); o.s[2] = f2bf(a.z); o.s[3] = f2bf(a.w);
  o.s[4] = f2bf(b.x); o.s[5] = f2bf(b.y); o.s[6] = f2bf(b.z); o.s[7] = f2bf(b.w);
  *(bf16x8*)(out + i) = o.v;
}

// ---------------- 256x192 deep-pipelined QKV GEMM (r11-verified, 130us) ----
__device__ __forceinline__ void stage_ab(
    const unsigned short* __restrict__ A, const unsigned short* __restrict__ W,
    unsigned short* la, unsigned short* lb, int m0, int n0, int k0,
    int wv, int lane) {
  const int K = 2048;
#pragma unroll
  for (int p = 0; p < 4; ++p) {                  // A: 32 KB
    const int off = wv * 1024 + p * 8192;        // wave-uniform LDS byte base
    const int o = off + lane * 16;               // linear dest byte offset
    const int row = o >> 7, ch = (o >> 4) & 7;
    const int csrc = (ch ^ (row & 7)) * 8;       // pre-swizzled source col
    gload_lds16(A + (size_t)(m0 + row) * K + k0 + csrc, la + (off >> 1));
  }
#pragma unroll
  for (int p = 0; p < 3; ++p) {                  // B: 24 KB
    const int off = wv * 1024 + p * 8192;
    const int o = off + lane * 16;
    const int row = o >> 7, ch = (o >> 4) & 7;
    const int csrc = (ch ^ (row & 7)) * 8;
    gload_lds16(W + (size_t)(n0 + row) * K + k0 + csrc, lb + (off >> 1));
  }
}

__global__ __launch_bounds__(512, 1) void gemm_qkv2(
    const unsigned short* __restrict__ A, const unsigned short* __restrict__ W,
    const float* __restrict__ bq, const float* __restrict__ bk,
    const float* __restrict__ bv, unsigned short* __restrict__ Q,
    unsigned short* __restrict__ Ko, unsigned short* __restrict__ V,
    float qsc) {
  __shared__ __attribute__((aligned(16))) unsigned short LA[2][16384];  // 256x64
  __shared__ __attribute__((aligned(16))) unsigned short LB[2][12288];  // 192x64
  const int m0 = blockIdx.y * 256, n0 = blockIdx.x * 192;
  const int tid = threadIdx.x, lane = tid & 63, wv = tid >> 6;
  const int wm = wv >> 2, wn = wv & 3;
  const int rA = lane & 15, g4 = lane >> 4;

  f32x4 acc[8][3];
#pragma unroll
  for (int i = 0; i < 8; ++i)
#pragma unroll
    for (int j = 0; j < 3; ++j)
#pragma unroll
      for (int r = 0; r < 4; ++r) acc[i][j][r] = 0.f;

  stage_ab(A, W, &LA[0][0], &LB[0][0], m0, n0, 0, wv, lane);
  stage_ab(A, W, &LA[1][0], &LB[1][0], m0, n0, 64, wv, lane);
  asm volatile("s_waitcnt vmcnt(7)" ::: "memory");
  __builtin_amdgcn_s_barrier();
  __builtin_amdgcn_sched_barrier(0);

  for (int t = 0; t < 32; ++t) {
    const unsigned short* la = &LA[t & 1][0];
    const unsigned short* lb = &LB[t & 1][0];
#pragma unroll
    for (int kk = 0; kk < 2; ++kk) {
      bf16x8 af[8], bfv[3];
      const int sw = ((kk * 4 + g4) ^ (rA & 7)) * 8;
#pragma unroll
      for (int i = 0; i < 8; ++i)
        af[i] = *(const bf16x8*)(la + (wm * 128 + i * 16 + rA) * 64 + sw);
#pragma unroll
      for (int j = 0; j < 3; ++j)
        bfv[j] = *(const bf16x8*)(lb + (wn * 48 + j * 16 + rA) * 64 + sw);
      __builtin_amdgcn_s_setprio(1);
#pragma unroll
      for (int i = 0; i < 8; ++i)
#pragma unroll
        for (int j = 0; j < 3; ++j)
          acc[i][j] = __builtin_amdgcn_mfma_f32_16x16x32_bf16(af[i], bfv[j], acc[i][j], 0, 0, 0);
      __builtin_amdgcn_s_setprio(0);
    }
    if (t == 31) break;
    __builtin_amdgcn_s_barrier();
    __builtin_amdgcn_sched_barrier(0);
    if (t + 2 < 32) {
      stage_ab(A, W, &LA[t & 1][0], &LB[t & 1][0], m0, n0, (t + 2) * 64, wv, lane);
      asm volatile("s_waitcnt vmcnt(7)" ::: "memory");
    } else {
      asm volatile("s_waitcnt vmcnt(0)" ::: "memory");
    }
    __builtin_amdgcn_s_barrier();
    __builtin_amdgcn_sched_barrier(0);
  }

  const int cR = g4 * 4, cC = rA;
#pragma unroll
  for (int j = 0; j < 3; ++j) {
    const int colb = n0 + wn * 48 + j * 16;
    const int seg = colb >> 11, clb = colb & 2047;
    const float* bp = (seg == 0) ? bq : (seg == 1) ? bk : bv;
    unsigned short* op = (seg == 0) ? Q : (seg == 1) ? Ko : V;
    const float es = (seg == 0) ? qsc : 1.0f;
    const int cl = clb + cC;
    const float bvv = bp[cl];
#pragma unroll
    for (int i = 0; i < 8; ++i) {
      const int row0 = m0 + wm * 128 + i * 16 + cR;
#pragma unroll
      for (int r = 0; r < 4; ++r)
        op[(size_t)(row0 + r) * D_DIM + cl] = f2bf((acc[i][j][r] + bvv) * es);
    }
  }
}

// ---------------- O-projection GEMM (fp32 out + bias, m97 128^2) -----------
__global__ __launch_bounds__(256, 2) void gemm_bt_f32(
    const unsigned short* __restrict__ A, const unsigned short* __restrict__ B,
    const float* __restrict__ bias, float* __restrict__ Cout,
    int M, int N, int K) {
  __shared__ __attribute__((aligned(16))) unsigned short As[128 * 32];
  __shared__ __attribute__((aligned(16))) unsigned short Bs[128 * 32];
  const int m0 = blockIdx.y * 128, n0 = blockIdx.x * 128;
  const int tid = threadIdx.x, lane = tid & 63, wv = tid >> 6;
  const int wm = wv >> 1, wn = wv & 1;
  const int rA = lane & 15, kb = (lane >> 4) * 8;

  f32x4 acc[4][4];
#pragma unroll
  for (int i = 0; i < 4; ++i)
#pragma unroll
    for (int j = 0; j < 4; ++j)
#pragma unroll
      for (int r = 0; r < 4; ++r) acc[i][j][r] = 0.f;

  for (int k0 = 0; k0 < K; k0 += 32) {
    __syncthreads();
#pragma unroll
    for (int p = 0; p < 2; ++p) {
      const int rr = (wv * 2 + p) * 16 + (lane >> 2);
      const int cc = lane & 3;
      gload_lds16(A + (size_t)(m0 + rr) * K + k0 + cc * 8, As + (wv * 2 + p) * 512);
      gload_lds16(B + (size_t)(n0 + rr) * K + k0 + cc * 8, Bs + (wv * 2 + p) * 512);
    }
    __syncthreads();
    bf16x8 af[4], bfr[4];
#pragma unroll
    for (int i = 0; i < 4; ++i)
      af[i] = *(const bf16x8*)(As + (wm * 64 + i * 16 + rA) * 32 + kb);
#pragma unroll
    for (int j = 0; j < 4; ++j)
      bfr[j] = *(const bf16x8*)(Bs + (wn * 64 + j * 16 + rA) * 32 + kb);
#pragma unroll
    for (int i = 0; i < 4; ++i)
#pragma unroll
      for (int j = 0; j < 4; ++j)
        acc[i][j] = __builtin_amdgcn_mfma_f32_16x16x32_bf16(af[i], bfr[j], acc[i][j], 0, 0, 0);
  }

  const int cR = (lane >> 4) * 4, cC = lane & 15;
#pragma unroll
  for (int j = 0; j < 4; ++j) {
    const int col = n0 + wn * 64 + j * 16 + cC;
    const float bvv = bias[col];
#pragma unroll
    for (int i = 0; i < 4; ++i) {
      const int row0 = m0 + wm * 64 + i * 16 + cR;
#pragma unroll
      for (int r = 0; r < 4; ++r)
        Cout[(size_t)(row0 + r) * N + col] = acc[i][j][r] + bvv;
    }
  }
}

// ---------------- split-k causal flash attention (r9 form + T14 V-hoist) ---
// Only change vs r9: the V global->register loads are hoisted ABOVE the
// tile's first __syncthreads (registers don't touch LDS -> no hazard), so
// their ~200-500cy latency overlaps the previous tile's PV compute instead
// of sitting exposed in the staging window.
__global__ __launch_bounds__(256, 2) void attn_part(
    const unsigned short* __restrict__ Qb, const unsigned short* __restrict__ Kb,
    const unsigned short* __restrict__ Vb, unsigned short* __restrict__ Opart,
    float* __restrict__ ML) {
  __shared__ __attribute__((aligned(16))) unsigned short Ks[64 * 128];
  __shared__ __attribute__((aligned(16))) unsigned short Vt[128 * 64];
  const int bid = blockIdx.x;
  const int h  = ((bid & 7) << 1) | ((bid >> 3) & 1);  // XCD-grouped heads
  const int hf = (bid >> 4) & 1;
  const int qi = 31 - (bid >> 5);                      // heavy first
  const int q0 = qi * 128;
  const int u2 = (h * 32 + qi) * 2 + hf;
  const int tid = threadIdx.x, lane = tid & 63, wv = tid >> 6;
  const int qc = lane & 31, hi = lane >> 5;
  const int q0w = q0 + wv * 32;
  const int myq = q0w + qc;
  const int kp = tid & 31, hb = (tid >> 5) * 16;

  bf16x8 qf[8];
#pragma unroll
  for (int sl = 0; sl < 8; ++sl)
    qf[sl] = *(const bf16x8*)(Qb + (size_t)myq * D_DIM + h * HDIM + sl * 16 + hi * 8);

  f32x16 oacc[4];
#pragma unroll
  for (int nf = 0; nf < 4; ++nf)
#pragma unroll
    for (int r = 0; r < 16; ++r) oacc[nf][r] = 0.f;
  float mh = -3.0e38f, l = 0.f;

  const int klo = hf * (qi + 1), khi = klo + qi + 1;
  const int wqmax = q0w + 31;

  for (int kt = klo; kt < khi; ++kt) {
    const int k0 = kt * 64;
    // ---- T14: issue V global loads BEFORE the barrier (regs only) ----
    union { uint4 u[4]; unsigned short s[32]; } t;
    {
      const unsigned short* s0 = Vb + (size_t)(k0 + 2 * kp) * D_DIM + h * HDIM + hb;
      t.u[0] = *(const uint4*)s0;           t.u[1] = *(const uint4*)(s0 + 8);
      t.u[2] = *(const uint4*)(s0 + D_DIM); t.u[3] = *(const uint4*)(s0 + D_DIM + 8);
    }
    __syncthreads();
#pragma unroll
    for (int p = 0; p < 4; ++p) {
      const int ob = wv * 4096 + p * 1024;
      const int o = ob + lane * 16;
      const int r = o >> 8, c = (o >> 4) & 15;
      gload_lds16(Kb + (size_t)(k0 + r) * D_DIM + h * HDIM + (c ^ (r & 7)) * 8,
                  Ks + ob / 2);
    }
#pragma unroll
    for (int w = 0; w < 16; ++w) {
      const int hd = hb + w;
      const unsigned val = (unsigned)t.s[w] | ((unsigned)t.s[16 + w] << 16);
      *(unsigned*)((char*)Vt + hd * 128 + (((kp >> 2) ^ (hd & 7)) << 4) + ((kp & 3) << 2)) = val;
    }
    __syncthreads();
    if (k0 > wqmax) continue;

    f32x16 sacc[2];
#pragma unroll
    for (int kb = 0; kb < 2; ++kb)
#pragma unroll
      for (int r = 0; r < 16; ++r) sacc[kb][r] = 0.f;
    __builtin_amdgcn_s_setprio(1);
#pragma unroll
    for (int sl = 0; sl < 8; ++sl) {
#pragma unroll
      for (int kb = 0; kb < 2; ++kb) {
        const int row = kb * 32 + qc;
        bf16x8 kfr = *(const bf16x8*)((const char*)Ks + row * 256 +
                                      (((2 * sl + hi) ^ (qc & 7)) << 4));
        sacc[kb] = __builtin_amdgcn_mfma_f32_32x32x16_bf16(kfr, qf[sl], sacc[kb], 0, 0, 0);
      }
    }
    __builtin_amdgcn_s_setprio(0);

    const bool needmask = (k0 + 63 > q0w);
    if (needmask) {
      const int dq = myq - k0;
#pragma unroll
      for (int kb = 0; kb < 2; ++kb)
#pragma unroll
        for (int r = 0; r < 16; ++r) {
          const int kk = kb * 32 + (r & 3) + 8 * (r >> 2) + 4 * hi;
          if (kk > dq) sacc[kb][r] = -3.0e38f;
        }
    }
    float mx0[8];
#pragma unroll
    for (int tx = 0; tx < 8; ++tx)
      mx0[tx] = fmaxf(fmaxf(sacc[0][tx], sacc[0][tx + 8]),
                      fmaxf(sacc[1][tx], sacc[1][tx + 8]));
    float mx = fmaxf(fmaxf(fmaxf(mx0[0], mx0[1]), fmaxf(mx0[2], mx0[3])),
                     fmaxf(fmaxf(mx0[4], mx0[5]), fmaxf(mx0[6], mx0[7])));
    mx = fmaxf(mx, __shfl_xor(mx, 32));
    if (!__all(mx <= mh + 11.5f)) {
      const float mnew = fmaxf(mh, mx);
      const float corr = exp2f(mh - mnew);
      mh = mnew;
      l *= corr;
#pragma unroll
      for (int r = 0; r < 16; ++r) {
        const float cr = __shfl(corr, (r & 3) + 8 * (r >> 2) + 4 * hi);
#pragma unroll
        for (int nf = 0; nf < 4; ++nf) oacc[nf][r] *= cr;
      }
    }
    float rs = 0.f;
#pragma unroll
    for (int kb = 0; kb < 2; ++kb)
#pragma unroll
      for (int r = 0; r < 16; ++r) {
        const float p = exp2f(sacc[kb][r] - mh);
        sacc[kb][r] = p;
        rs += p;
      }
    rs += __shfl_xor(rs, 32);
    l += rs;

    bf16x8 pa[4];
#pragma unroll
    for (int kb = 0; kb < 2; ++kb)
#pragma unroll
      for (int s = 0; s < 2; ++s) {
        const int b = s * 8;
        unsigned pk0 = cvtpk_bf16(sacc[kb][b + 0], sacc[kb][b + 1]);
        unsigned pk1 = cvtpk_bf16(sacc[kb][b + 2], sacc[kb][b + 3]);
        unsigned pk2 = cvtpk_bf16(sacc[kb][b + 4], sacc[kb][b + 5]);
        unsigned pk3 = cvtpk_bf16(sacc[kb][b + 6], sacc[kb][b + 7]);
        const unsigned sw0 = (unsigned)__shfl_xor((int)pk0, 32);
        const unsigned sw1 = (unsigned)__shfl_xor((int)pk1, 32);
        const unsigned sw2 = (unsigned)__shfl_xor((int)pk2, 32);
        const unsigned sw3 = (unsigned)__shfl_xor((int)pk3, 32);
        union { unsigned u[4]; bf16x8 v; } f;
        if (hi) { f.u[0] = sw2; f.u[1] = sw3; f.u[2] = pk2; f.u[3] = pk3; }
        else    { f.u[0] = pk0; f.u[1] = pk1; f.u[2] = sw0; f.u[3] = sw1; }
        pa[kb * 2 + s] = f.v;
      }

    __builtin_amdgcn_s_setprio(1);
#pragma unroll
    for (int nf = 0; nf < 4; ++nf) {
      const int hd = 32 * nf + qc;
#pragma unroll
      for (int ks = 0; ks < 4; ++ks) {
        bf16x8 vf = *(const bf16x8*)((const char*)Vt + hd * 128 +
                                     (((2 * ks + hi) ^ (qc & 7)) << 4));
        oacc[nf] = __builtin_amdgcn_mfma_f32_32x32x16_bf16(pa[ks], vf, oacc[nf], 0, 0, 0);
      }
    }
    __builtin_amdgcn_s_setprio(0);
  }

  unsigned short* ob = Opart + (size_t)u2 * 16384;
#pragma unroll
  for (int r = 0; r < 16; ++r) {
    const int rl = wv * 32 + (r & 3) + 8 * (r >> 2) + 4 * hi;
#pragma unroll
    for (int nf = 0; nf < 4; ++nf)
      ob[rl * 128 + 32 * nf + qc] = f2bf(oacc[nf][r]);
  }
  if (hi == 0) {
    ML[(size_t)u2 * 256 + wv * 32 + qc] = mh;
    ML[(size_t)u2 * 256 + 128 + wv * 32 + qc] = l;
  }
}

// ---------------- combine the two k-halves -------------------------------
__global__ __launch_bounds__(256) void attn_combine(
    const unsigned short* __restrict__ Opart, const float* __restrict__ ML,
    unsigned short* __restrict__ Ob) {
  const int u = blockIdx.x;            // h*32 + qi
  const int h = u >> 5, qi = u & 31;
  const int tid = threadIdx.x;
  const int row = tid >> 1, c0 = (tid & 1) * 64;
  const float m1 = ML[(size_t)(u * 2 + 0) * 256 + row];
  const float l1 = ML[(size_t)(u * 2 + 0) * 256 + 128 + row];
  const float m2 = ML[(size_t)(u * 2 + 1) * 256 + row];
  const float l2 = ML[(size_t)(u * 2 + 1) * 256 + 128 + row];
  const float M  = fmaxf(m1, m2);
  const float a1 = exp2f(m1 - M), a2 = exp2f(m2 - M);
  const float inv = 1.f / (a1 * l1 + a2 * l2);
  const unsigned short* p1 = Opart + (size_t)(u * 2 + 0) * 16384 + row * 128 + c0;
  const unsigned short* p2 = Opart + (size_t)(u * 2 + 1) * 16384 + row * 128 + c0;
  unsigned short* o = Ob + (size_t)(qi * 128 + row) * D_DIM + h * HDIM + c0;
#pragma unroll
  for (int c = 0; c < 64; c += 8) {
    bf16x8 v1 = *(const bf16x8*)(p1 + c);
    bf16x8 v2 = *(const bf16x8*)(p2 + c);
    union { unsigned short s[8]; bf16x8 v; } out;
#pragma unroll
    for (int e = 0; e < 8; ++e)
      out.s[e] = f2bf((bf2f((unsigned short)v1[e]) * a1 +
                       bf2f((unsigned short)v2[e]) * a2) * inv);
    *(bf16x8*)(o + c) = out.v;
  }
}

extern "C" void kernel_launch(void* const* d_in, const int* in_sizes, int n_in,
                              void* d_out, int out_size, void* d_ws, size_t ws_size,
                              hipStream_t stream) {
  const float* X  = (const float*)d_in[0];
  const float* Wq = (const float*)d_in[1];
  const float* bq = (const float*)d_in[2];
  const float* Wk = (const float*)d_in[3];
  const float* bk = (const float*)d_in[4];
  const float* Wv = (const float*)d_in[5];
  const float* bv = (const float*)d_in[6];
  const float* Wo = (const float*)d_in[7];
  const float* bo = (const float*)d_in[8];
  float* out = (float*)d_out;

  unsigned short* ws = (unsigned short*)d_ws;
  const size_t SD = (size_t)S_LEN * D_DIM;
  const size_t DD = (size_t)D_DIM * D_DIM;
  unsigned short* Xb  = ws;
  unsigned short* Wqb = Xb + SD;        // Wq,Wk,Wv contiguous = fused [6144][2048]
  unsigned short* Wob = Wqb + 3 * DD;
  unsigned short* Qb  = Wob + DD;
  unsigned short* Kb  = Qb + SD;
  unsigned short* Vb  = Kb + SD;
  unsigned short* AOb = Vb + SD;
  unsigned short* Opart = ws;                 // 1024 units * 16384 = SD+2DD elems
  float* ML = (float*)(ws + SD + 2 * DD);     // 1024*256 f32 (tail of fused W)

  cvt_all<<<(int)(6 * DD / 8 / 256), 256, 0, stream>>>(X, Wq, Wk, Wv, Wo, Xb);

  const float qsc = 0.08838834764831845f * 1.4426950408889634f;  // scale*log2(e)
  gemm_qkv2<<<dim3(32, 16), 512, 0, stream>>>(Xb, Wqb, bq, bk, bv, Qb, Kb, Vb, qsc);

  attn_part<<<dim3(1024), 256, 0, stream>>>(Qb, Kb, Vb, Opart, ML);
  attn_combine<<<dim3(512), 256, 0, stream>>>(Opart, ML, AOb);

  gemm_bt_f32<<<dim3(16, 32), 256, 0, stream>>>(AOb, Wob, bo, out, S_LEN, D_DIM, D_DIM);
}